// Round 2
// baseline (1644.422 us; speedup 1.0000x reference)
//
#include <hip/hip_runtime.h>
#include <hip/hip_bf16.h>

using bf16 = __hip_bfloat16;

#define B_      32
#define HH      56
#define WW      56
#define HIDDEN  96
#define HEADS   3
#define HD      32
#define WS_     7
#define DISP    3
#define NWH     8
#define NWW     8
#define NW      64
#define WS2     49
#define TOKENS  (B_*HH*WW)                        /* 100352 */
#define QKV_ELEMS ((size_t)B_*HEADS*NW*WS2*HD)    /* 9,633,792 */

template <typename T> __device__ inline T    encT(float v);
template <> __device__ inline float encT<float>(float v) { return v; }
template <> __device__ inline bf16  encT<bf16>(float v)  { return __float2bfloat16(v); }
template <typename T> __device__ inline float decT(T v);
template <> __device__ inline float decT<float>(float v) { return v; }
template <> __device__ inline float decT<bf16>(bf16 v)   { return __bfloat162float(v); }

// ---------------- Kernel 1: shifted gather + QKV projection + windowing ----
template <typename T>
__global__ __launch_bounds__(256) void qkv_win_kernel(
    const float* __restrict__ x, const float* __restrict__ w_qkv,
    const float* __restrict__ b_qkv,
    T* __restrict__ q, T* __restrict__ k, T* __restrict__ v) {
  __shared__ float xs[16][97];   // +1 pad breaks bank aliasing
  int tid = threadIdx.x;
  int t0 = blockIdx.x * 16;

  for (int idx = tid; idx < 16 * 96; idx += 256) {
    int tl = idx / 96, ch = idx % 96;
    int tok = t0 + tl;
    int b = tok / (HH * WW); int rem = tok % (HH * WW);
    int hs = rem / WW, wsp = rem % WW;
    int h = (hs + DISP) % HH, w = (wsp + DISP) % WW;   // roll(x, -3, -3)
    xs[tl][ch] = x[((size_t)(b * HH + h) * WW + w) * HIDDEN + ch];
  }
  __syncthreads();

  int tl = tid & 15;      // token within tile
  int cg = tid >> 4;      // column group: 16 groups x 18 cols = 288
  int tok = t0 + tl;
  int b = tok / (HH * WW); int rem = tok % (HH * WW);
  int hs = rem / WW, wsp = rem % WW;
  int wy = hs / WS_, py = hs % WS_, wx = wsp / WS_, px = wsp % WS_;
  int nw = wy * NWW + wx, pos = py * WS_ + px;

  for (int cc = 0; cc < 18; cc++) {
    int c = cg * 18 + cc;
    float acc = b_qkv[c];
#pragma unroll
    for (int kk = 0; kk < 96; kk++)
      acc += xs[tl][kk] * w_qkv[kk * 288 + c];
    int which = c / 96;            // 0=q 1=k 2=v
    int head = (c % 96) / HD;
    int d = c % HD;
    T* dst = (which == 0) ? q : ((which == 1) ? k : v);
    dst[(((size_t)(b * HEADS + head) * NW + nw) * WS2 + pos) * HD + d] = encT<T>(acc);
  }
}

// ---------------- Kernel 2: per-window attention --------------------------
template <typename T>
__global__ __launch_bounds__(256) void attn_kernel(
    const T* __restrict__ q, const T* __restrict__ k,
    const T* __restrict__ v, const float* __restrict__ pos_emb,
    T* __restrict__ attn_out) {
  int blk = blockIdx.x;                 // b*192 + head*64 + nw
  int nw = blk % NW; int t2 = blk / NW;
  int head = t2 % HEADS; int b = t2 / HEADS;

  __shared__ float qs[WS2][33], ks[WS2][33], vs[WS2][33];
  __shared__ float att[WS2][50];
  __shared__ float pel[169];
  int tid = threadIdx.x;

  size_t base = ((size_t)(b * HEADS + head) * NW + nw) * (WS2 * HD);
  for (int i = tid; i < WS2 * HD; i += 256) {
    qs[i / HD][i % HD] = decT<T>(q[base + i]);
    ks[i / HD][i % HD] = decT<T>(k[base + i]);
    vs[i / HD][i % HD] = decT<T>(v[base + i]);
  }
  for (int i = tid; i < 169; i += 256) pel[i] = pos_emb[i];
  __syncthreads();

  const float scale = 0.10206207261596575f;   // 96^-0.5 (HIDDEN, per reference)
  bool masked = (nw >= NW - NWW);             // bottom row of windows only

  for (int s = tid; s < WS2 * WS2; s += 256) {
    int i = s / WS2, j = s % WS2;
    float acc = 0.f;
#pragma unroll
    for (int d = 0; d < HD; d++) acc += qs[i][d] * ks[j][d];
    acc *= scale;
    int yi = i / WS_, xi = i % WS_, yj = j / WS_, xj = j % WS_;
    acc += pel[(yj - yi + 6) * 13 + (xj - xi + 6)];   // rel = idx[j]-idx[i]+6
    if (masked && ((i >= 28) != (j >= 28))) acc = -1e30f;
    att[i][j] = acc;
  }
  __syncthreads();

  if (tid < WS2) {
    float m = -1e30f;
    for (int j = 0; j < WS2; j++) m = fmaxf(m, att[tid][j]);
    float ssum = 0.f;
    for (int j = 0; j < WS2; j++) {
      float e = __expf(att[tid][j] - m);
      att[tid][j] = e; ssum += e;
    }
    float inv = 1.0f / ssum;
    for (int j = 0; j < WS2; j++) att[tid][j] *= inv;
  }
  __syncthreads();

  int wy = nw / NWW, wx = nw % NWW;
  for (int s = tid; s < WS2 * HD; s += 256) {
    int i = s / HD, d = s % HD;
    float acc = 0.f;
#pragma unroll
    for (int j = 0; j < WS2; j++) acc += att[i][j] * vs[j][d];
    int py = i / WS_, px = i % WS_;
    int hsp = wy * WS_ + py, wsp = wx * WS_ + px;
    attn_out[((size_t)(b * HH + hsp) * WW + wsp) * HIDDEN + head * HD + d] = encT<T>(acc);
  }
}

// ---------------- Kernel 3: un-shift gather + output projection -----------
template <typename T>
__global__ __launch_bounds__(256) void proj_kernel(
    const T* __restrict__ attn, const float* __restrict__ w_out,
    const float* __restrict__ b_out, float* __restrict__ out) {
  __shared__ float xs[16][97];
  int tid = threadIdx.x;
  int t0 = blockIdx.x * 16;

  for (int idx = tid; idx < 16 * 96; idx += 256) {
    int tl = idx / 96, ch = idx % 96;
    int tok = t0 + tl;
    int b = tok / (HH * WW); int rem = tok % (HH * WW);
    int h = rem / WW, w = rem % WW;
    int hs = (h - DISP + HH) % HH, wsp = (w - DISP + WW) % WW;  // roll(out,+3,+3)
    xs[tl][ch] = decT<T>(attn[((size_t)(b * HH + hs) * WW + wsp) * HIDDEN + ch]);
  }
  __syncthreads();

  int tl = tid & 15, cg = tid >> 4;   // 16 groups x 6 cols = 96
  size_t obase = (size_t)(t0 + tl) * HIDDEN;
  for (int cc = 0; cc < 6; cc++) {
    int c = cg * 6 + cc;
    float acc = b_out[c];
#pragma unroll
    for (int kk = 0; kk < 96; kk++)
      acc += xs[tl][kk] * w_out[kk * 96 + c];
    out[obase + c] = acc;
  }
}

extern "C" void kernel_launch(void* const* d_in, const int* in_sizes, int n_in,
                              void* d_out, int out_size, void* d_ws, size_t ws_size,
                              hipStream_t stream) {
  const float* x     = (const float*)d_in[0];
  const float* w_qkv = (const float*)d_in[1];
  const float* b_qkv = (const float*)d_in[2];
  const float* pos   = (const float*)d_in[3];
  const float* w_out = (const float*)d_in[4];
  const float* b_out = (const float*)d_in[5];
  float* out = (float*)d_out;

  size_t need_f32 = 4 * QKV_ELEMS * sizeof(float);   // ~154 MB
  if (ws_size >= need_f32) {
    float* qb = (float*)d_ws;
    float* kb = qb + QKV_ELEMS;
    float* vb = kb + QKV_ELEMS;
    float* ab = vb + QKV_ELEMS;
    qkv_win_kernel<float><<<TOKENS / 16, 256, 0, stream>>>(x, w_qkv, b_qkv, qb, kb, vb);
    attn_kernel<float><<<B_ * HEADS * NW, 256, 0, stream>>>(qb, kb, vb, pos, ab);
    proj_kernel<float><<<TOKENS / 16, 256, 0, stream>>>(ab, w_out, b_out, out);
  } else {
    bf16* qb = (bf16*)d_ws;
    bf16* kb = qb + QKV_ELEMS;
    bf16* vb = kb + QKV_ELEMS;
    bf16* ab = vb + QKV_ELEMS;
    qkv_win_kernel<bf16><<<TOKENS / 16, 256, 0, stream>>>(x, w_qkv, b_qkv, qb, kb, vb);
    attn_kernel<bf16><<<B_ * HEADS * NW, 256, 0, stream>>>(qb, kb, vb, pos, ab);
    proj_kernel<bf16><<<TOKENS / 16, 256, 0, stream>>>(ab, w_out, b_out, out);
  }
}

// Round 3
// 445.767 us; speedup vs baseline: 3.6890x; 3.6890x over previous
//
#include <hip/hip_runtime.h>
#include <hip/hip_bf16.h>

using bf16 = __hip_bfloat16;

#define B_      32
#define HH      56
#define WW      56
#define HIDDEN  96
#define HEADS   3
#define HD      32
#define WS_     7
#define DISP    3
#define NWH     8
#define NWW     8
#define NW      64
#define WS2     49
#define TOKENS  (B_*HH*WW)                        /* 100352 */
#define QKV_ELEMS ((size_t)B_*HEADS*NW*WS2*HD)    /* 9,633,792 */

template <typename T> __device__ inline T    encT(float v);
template <> __device__ inline float encT<float>(float v) { return v; }
template <> __device__ inline bf16  encT<bf16>(float v)  { return __float2bfloat16(v); }
template <typename T> __device__ inline float decT(T v);
template <> __device__ inline float decT<float>(float v) { return v; }
template <> __device__ inline float decT<bf16>(bf16 v)   { return __bfloat162float(v); }

// ---------------- Kernel 1: shifted gather + QKV projection + windowing ----
// 64 tokens/block, 9 column-tiles of 32. Each col-tile is exactly one
// (q/k/v, head) pair, so d = col and stores are coalesced.
template <typename T>
__global__ __launch_bounds__(256) void qkv_win_kernel(
    const float* __restrict__ x, const float* __restrict__ w_qkv,
    const float* __restrict__ b_qkv,
    T* __restrict__ q, T* __restrict__ k, T* __restrict__ v) {
  __shared__ float xs[64][100];   // stride 100: 16B-aligned float4 rows
  __shared__ float wT[32][97];    // stride 97: conflict-free scalar reads
  int tid = threadIdx.x;
  int t0 = blockIdx.x * 64;

  for (int idx = tid; idx < 64 * 96; idx += 256) {
    int tl = idx / 96, ch = idx % 96;
    int tok = t0 + tl;
    int b = tok / (HH * WW); int rem = tok % (HH * WW);
    int hs = rem / WW, wsp = rem % WW;
    int h = (hs + DISP) % HH, w = (wsp + DISP) % WW;   // roll(x, -3, -3)
    xs[tl][ch] = x[((size_t)(b * HH + h) * WW + w) * HIDDEN + ch];
  }

  int col = tid & 31, tg = tid >> 5;

  // per-token output bases (head-independent part), computed once
  size_t base8[8];
#pragma unroll
  for (int t = 0; t < 8; t++) {
    int tok = t0 + tg * 8 + t;
    int b = tok / (HH * WW); int rem = tok % (HH * WW);
    int hs = rem / WW, wsp = rem % WW;
    int wy = hs / WS_, py = hs % WS_, wx = wsp / WS_, px = wsp % WS_;
    int nw = wy * NWW + wx, pos = py * WS_ + px;
    base8[t] = (size_t)b * (HEADS * NW * WS2 * HD) + (size_t)(nw * WS2 + pos) * HD;
  }

  for (int tile = 0; tile < 9; tile++) {
    int n0 = tile * 32;
    __syncthreads();   // xs ready (tile 0) / wT free (tile >0)
    for (int idx = tid; idx < 32 * 96; idx += 256) {
      int kk = idx >> 5, c = idx & 31;       // lanes along c: coalesced global
      wT[c][kk] = w_qkv[kk * 288 + n0 + c];
    }
    __syncthreads();

    float bias = b_qkv[n0 + col];
    float acc[8];
#pragma unroll
    for (int t = 0; t < 8; t++) acc[t] = bias;

#pragma unroll 4
    for (int kk = 0; kk < 96; kk += 4) {
      float w0 = wT[col][kk + 0], w1 = wT[col][kk + 1];
      float w2 = wT[col][kk + 2], w3 = wT[col][kk + 3];
#pragma unroll
      for (int t = 0; t < 8; t++) {
        const float4 xv = *(const float4*)&xs[tg * 8 + t][kk];  // broadcast read
        acc[t] = fmaf(xv.x, w0, acc[t]);
        acc[t] = fmaf(xv.y, w1, acc[t]);
        acc[t] = fmaf(xv.z, w2, acc[t]);
        acc[t] = fmaf(xv.w, w3, acc[t]);
      }
    }

    int which = n0 / 96;                 // 0=q 1=k 2=v
    int head = (n0 % 96) / HD;
    T* dst = (which == 0) ? q : ((which == 1) ? k : v);
    size_t hoff = (size_t)head * (NW * WS2 * HD) + col;
#pragma unroll
    for (int t = 0; t < 8; t++)
      dst[base8[t] + hoff] = encT<T>(acc[t]);
  }
}

// ---------------- Kernel 2: per-window attention --------------------------
template <typename T>
__global__ __launch_bounds__(256) void attn_kernel(
    const T* __restrict__ q, const T* __restrict__ k,
    const T* __restrict__ v, const float* __restrict__ pos_emb,
    T* __restrict__ attn_out) {
  int blk = blockIdx.x;                 // b*192 + head*64 + nw
  int nw = blk % NW; int t2 = blk / NW;
  int head = t2 % HEADS; int b = t2 / HEADS;

  __shared__ float qs[WS2][33], ks[WS2][33], vs[WS2][33];
  __shared__ float es[WS2][50];
  __shared__ float pel[169];
  __shared__ float inv[WS2];
  int tid = threadIdx.x;

  size_t base = ((size_t)(b * HEADS + head) * NW + nw) * (WS2 * HD);
  for (int i = tid; i < WS2 * HD; i += 256) {
    int r = i >> 5, d = i & 31;
    qs[r][d] = decT<T>(q[base + i]);
    ks[r][d] = decT<T>(k[base + i]);
    vs[r][d] = decT<T>(v[base + i]);
  }
  for (int i = tid; i < 169; i += 256) pel[i] = pos_emb[i];
  __syncthreads();

  const float scale = 0.10206207261596575f;   // 96^-0.5 (HIDDEN, per reference)
  bool masked = (nw >= NW - NWW);             // bottom row of windows only

  // scores -> exp directly (scores are O(+-6): exp safe without max-sub)
  for (int s = tid; s < WS2 * WS2; s += 256) {
    int i = s / WS2, j = s % WS2;
    float acc = 0.f;
#pragma unroll
    for (int d = 0; d < HD; d++) acc += qs[i][d] * ks[j][d];
    int yi = i / WS_, xi = i % WS_, yj = j / WS_, xj = j % WS_;
    float sc = acc * scale + pel[(yj - yi + 6) * 13 + (xj - xi + 6)];
    es[i][j] = (masked && ((i >= 28) != (j >= 28))) ? 0.f : __expf(sc);
  }
  __syncthreads();

  if (tid < WS2) {
    float ssum = 0.f;
    for (int j = 0; j < WS2; j++) ssum += es[tid][j];
    inv[tid] = 1.0f / ssum;
  }
  __syncthreads();

  int wy = nw / NWW, wx = nw % NWW;
  for (int s = tid; s < WS2 * HD; s += 256) {
    int i = s >> 5, d = s & 31;
    float acc = 0.f;
#pragma unroll
    for (int j = 0; j < WS2; j++) acc += es[i][j] * vs[j][d];
    int py = i / WS_, px = i % WS_;
    int hsp = wy * WS_ + py, wsp = wx * WS_ + px;
    attn_out[((size_t)(b * HH + hsp) * WW + wsp) * HIDDEN + head * HD + d] =
        encT<T>(acc * inv[i]);
  }
}

// ---------------- Kernel 3: un-shift gather + output projection -----------
template <typename T>
__global__ __launch_bounds__(256) void proj_kernel(
    const T* __restrict__ attn, const float* __restrict__ w_out,
    const float* __restrict__ b_out, float* __restrict__ out) {
  __shared__ float xs[64][100];
  __shared__ float wT[32][97];
  int tid = threadIdx.x;
  int t0 = blockIdx.x * 64;

  for (int idx = tid; idx < 64 * 96; idx += 256) {
    int tl = idx / 96, ch = idx % 96;
    int tok = t0 + tl;
    int b = tok / (HH * WW); int rem = tok % (HH * WW);
    int h = rem / WW, w = rem % WW;
    int hs = (h - DISP + HH) % HH, wsp = (w - DISP + WW) % WW;  // roll(out,+3,+3)
    xs[tl][ch] = decT<T>(attn[((size_t)(b * HH + hs) * WW + wsp) * HIDDEN + ch]);
  }

  int col = tid & 31, tg = tid >> 5;

  for (int tile = 0; tile < 3; tile++) {
    int n0 = tile * 32;
    __syncthreads();
    for (int idx = tid; idx < 32 * 96; idx += 256) {
      int kk = idx >> 5, c = idx & 31;
      wT[c][kk] = w_out[kk * 96 + n0 + c];
    }
    __syncthreads();

    float bias = b_out[n0 + col];
    float acc[8];
#pragma unroll
    for (int t = 0; t < 8; t++) acc[t] = bias;

#pragma unroll 4
    for (int kk = 0; kk < 96; kk += 4) {
      float w0 = wT[col][kk + 0], w1 = wT[col][kk + 1];
      float w2 = wT[col][kk + 2], w3 = wT[col][kk + 3];
#pragma unroll
      for (int t = 0; t < 8; t++) {
        const float4 xv = *(const float4*)&xs[tg * 8 + t][kk];
        acc[t] = fmaf(xv.x, w0, acc[t]);
        acc[t] = fmaf(xv.y, w1, acc[t]);
        acc[t] = fmaf(xv.z, w2, acc[t]);
        acc[t] = fmaf(xv.w, w3, acc[t]);
      }
    }

#pragma unroll
    for (int t = 0; t < 8; t++)
      out[(size_t)(t0 + tg * 8 + t) * HIDDEN + n0 + col] = acc[t];
  }
}

extern "C" void kernel_launch(void* const* d_in, const int* in_sizes, int n_in,
                              void* d_out, int out_size, void* d_ws, size_t ws_size,
                              hipStream_t stream) {
  const float* x     = (const float*)d_in[0];
  const float* w_qkv = (const float*)d_in[1];
  const float* b_qkv = (const float*)d_in[2];
  const float* pos   = (const float*)d_in[3];
  const float* w_out = (const float*)d_in[4];
  const float* b_out = (const float*)d_in[5];
  float* out = (float*)d_out;

  size_t need_f32 = 4 * QKV_ELEMS * sizeof(float);   // ~154 MB
  if (ws_size >= need_f32) {
    float* qb = (float*)d_ws;
    float* kb = qb + QKV_ELEMS;
    float* vb = kb + QKV_ELEMS;
    float* ab = vb + QKV_ELEMS;
    qkv_win_kernel<float><<<TOKENS / 64, 256, 0, stream>>>(x, w_qkv, b_qkv, qb, kb, vb);
    attn_kernel<float><<<B_ * HEADS * NW, 256, 0, stream>>>(qb, kb, vb, pos, ab);
    proj_kernel<float><<<TOKENS / 64, 256, 0, stream>>>(ab, w_out, b_out, out);
  } else {
    bf16* qb = (bf16*)d_ws;
    bf16* kb = qb + QKV_ELEMS;
    bf16* vb = kb + QKV_ELEMS;
    bf16* ab = vb + QKV_ELEMS;
    qkv_win_kernel<bf16><<<TOKENS / 64, 256, 0, stream>>>(x, w_qkv, b_qkv, qb, kb, vb);
    attn_kernel<bf16><<<B_ * HEADS * NW, 256, 0, stream>>>(qb, kb, vb, pos, ab);
    proj_kernel<bf16><<<TOKENS / 64, 256, 0, stream>>>(ab, w_out, b_out, out);
  }
}